// Round 11
// baseline (162.917 us; speedup 1.0000x reference)
//
#include <hip/hip_runtime.h>

// ---------------------------------------------------------------------------
// AttentionLayer: out = softmax((xWq+bq)(xWk+bk)^T/8 + mask) (xWv+bv)
// B=4, S=2048, D=1024, H=16, Dh=64.  All-bf16 MFMA pipeline, fp32 accum.
// R25: PRODUCER-CONSUMER WAVE SPECIALIZATION in attn.  8-wave (512-thread)
//      blocks: waves 0-3 = QK (qf + score accum + exp/pack, NO cacc);
//      waves 4-7 = PV (cacc + V reads, NO qf/QK state).  Per-wave live set
//      ~100 < 128 => 4 waves/SIMD band reachable for the FIRST time (every
//      monolithic variant needed 130-170 => locked at 2/SIMD).  P handoff
//      through LDS is lane-identity (producer lane L's pf == what consumer
//      lane L feeds the same MFMA) — no layout math.  Pipeline: PV lags QK
//      by one kb phase; P dbuf by kb parity, V dbuf by kt parity (chain
//      hand-simulated incl. kt boundary + drain).  5 barriers/kt.
// LAWS: monolithic-wave design floor = 93.6 (R19).  Occupancy bands are
//      powers of 2; monolithic needs >128 total => 2/SIMD structural.
//      R24: T14 reg-staging at (256,2) granted+no-spill but NET -7% (occ
//      tax > latency gain) => T14 closed.  dbuf inflates regs (R21/R23).
//      Zero-LDS 3x worse (R20).  Wide-Q spills (R18).  T15 null (R17).
//      Q-in-LDS -2% (R22).  7 scheduling variants null/neg.
// ---------------------------------------------------------------------------

typedef __attribute__((ext_vector_type(8))) short bf16x8;
typedef __attribute__((ext_vector_type(4))) float f32x4;
typedef __attribute__((ext_vector_type(16))) float f32x16;

#define LOG2E 1.4426950408889634f

__device__ __forceinline__ ushort f2bf(float f) {
  union { float f; unsigned int u; } x; x.f = f;
  unsigned int r = x.u + 0x7fffu + ((x.u >> 16) & 1u);   // RNE
  return (ushort)(r >> 16);
}

// async global->LDS, 16B per lane; LDS dest = wave-uniform base + lane*16
__device__ __forceinline__ void gload16(const ushort* g, ushort* l) {
  __builtin_amdgcn_global_load_lds(
      (__attribute__((address_space(1))) unsigned int*)(g),
      (__attribute__((address_space(3))) unsigned int*)(l), 16, 0, 0);
}

// ---------------------------------------------------------------------------
// prep: blocks 0..8191 = x->bf16; 8192..11263 = W transpose; 11264 = mask scan
__global__ __launch_bounds__(256) void prep(
    const float* __restrict__ x, ushort* __restrict__ xb,
    const float* __restrict__ Wq, const float* __restrict__ Wk,
    const float* __restrict__ Wv, ushort* __restrict__ WT,
    const int* __restrict__ mask, int* __restrict__ flagw) {
  __shared__ float tile[32][33];
  __shared__ int accum[64];
  const int blk = blockIdx.x, t = threadIdx.x;
  if (blk < 8192) {
    int i = blk * 256 + t;
    float4 v = ((const float4*)x)[i];
    ushort4 o;
    o.x = f2bf(v.x); o.y = f2bf(v.y); o.z = f2bf(v.z); o.w = f2bf(v.w);
    ((ushort4*)xb)[i] = o;
  } else if (blk < 11264) {
    int bb = blk - 8192;
    int z = bb >> 10, rem = bb & 1023, db = rem >> 5, nb = rem & 31;
    const float* W = (z == 0) ? Wq : ((z == 1) ? Wk : Wv);
    int tx = t & 31, ty = t >> 5;   // 32 x 8
#pragma unroll
    for (int i = 0; i < 4; i++) {
      int dl = ty + i * 8;
      tile[dl][tx] = W[(size_t)(db * 32 + dl) * 1024 + nb * 32 + tx];
    }
    __syncthreads();
#pragma unroll
    for (int i = 0; i < 4; i++) {
      int nl = ty + i * 8;
      WT[(size_t)(z * 1024 + nb * 32 + nl) * 1024 + db * 32 + tx] = f2bf(tile[tx][nl]);
    }
  } else {
    if (t < 64) accum[t] = 0;
    __syncthreads();
    int p = t >> 2, j = t & 3;          // p = b*16+kt
    int base = p * 128 + j * 32;
    int s = 0;
#pragma unroll
    for (int i = 0; i < 8; i++) {
      int4 v = *(const int4*)(mask + base + i * 4);
      s += v.x + v.y + v.z + v.w;
    }
    atomicAdd(&accum[p], s);
    __syncthreads();
    if (t < 4) {
      int w = 0;
#pragma unroll
      for (int kt = 0; kt < 16; kt++)
        if (accum[t * 16 + kt] != 128) w |= (1 << kt);
      flagw[t] = w;
    }
  }
}

// ---------------------------------------------------------------------------
// fused QKV GEMM, m97 structure + early-issue staging (R8 version, (256,2)).
// blocks 0..1023: mode0 (Q,K: M=8192 N=2048); 1024..1535: mode1 (V^T).
__global__ __launch_bounds__(256, 2) void gemm_qkv(
    const ushort* __restrict__ xb, const ushort* __restrict__ WT,
    const float* __restrict__ bq, const float* __restrict__ bk,
    const float* __restrict__ bv, ushort* __restrict__ Qg,
    ushort* __restrict__ Kg, ushort* __restrict__ VTg) {
  __shared__ __align__(16) ushort As[128 * 64];
  __shared__ __align__(16) ushort Bs[128 * 64];
  const int t = threadIdx.x, wid = t >> 6, lane = t & 63;
  const int blk = blockIdx.x;
  int mode, mb, nb;
  const ushort *A, *B;
  if (blk < 1024) {
    mode = 0;
    int lin2 = (blk & 7) * 128 + (blk >> 3);   // XCD owns 8 mb-panels
    nb = lin2 & 15; mb = lin2 >> 4;
    A = xb; B = WT;
  } else {
    mode = 1;
    int l = blk - 1024;
    int lin2 = (l & 7) * 64 + (l >> 3);        // XCD owns 8 nb-panels
    mb = lin2 & 7; nb = lin2 >> 3;
    A = WT + (size_t)2048 * 1024; B = xb;
  }
  const ushort* Ab = A + (size_t)mb * 128 * 1024;
  const ushort* Bb = B + (size_t)nb * 128 * 1024;
  const int wr = wid >> 1, wc = wid & 1;

  f32x4 acc[4][4] = {};

  const int srow = lane >> 3;              // 0..7 row-in-8
  const int schunk = (lane & 7) ^ srow;    // pre-swizzled source chunk

  // prologue: issue stage(0)
#pragma unroll
  for (int i = 0; i < 4; i++) {
    int blki = i * 4 + wid;
    int row = blki * 8 + srow;
    int ldso = __builtin_amdgcn_readfirstlane(blki * 512);
    gload16(Ab + (size_t)row * 1024 + schunk * 8, As + ldso);
    gload16(Bb + (size_t)row * 1024 + schunk * 8, Bs + ldso);
  }

  for (int kt = 0; kt < 16; ++kt) {
    __syncthreads();                       // (1) stage(kt) arrived

    bf16x8 af[2][4], bf[2][4];
#pragma unroll
    for (int ks = 0; ks < 2; ks++) {
#pragma unroll
      for (int m = 0; m < 4; m++) {
        int row = wr * 64 + m * 16 + (lane & 15);
        int slot = (ks * 4 + (lane >> 4)) ^ (row & 7);
        af[ks][m] = *(const bf16x8*)(As + row * 64 + slot * 8);
      }
#pragma unroll
      for (int n = 0; n < 4; n++) {
        int row = wc * 64 + n * 16 + (lane & 15);
        int slot = (ks * 4 + (lane >> 4)) ^ (row & 7);
        bf[ks][n] = *(const bf16x8*)(Bs + row * 64 + slot * 8);
      }
    }
    __syncthreads();                       // (2) all fragment reads in regs

    if (kt < 15) {
      const int kof = (kt + 1) * 64 + schunk * 8;
#pragma unroll
      for (int i = 0; i < 4; i++) {
        int blki = i * 4 + wid;
        int row = blki * 8 + srow;
        int ldso = __builtin_amdgcn_readfirstlane(blki * 512);
        gload16(Ab + (size_t)row * 1024 + kof, As + ldso);
        gload16(Bb + (size_t)row * 1024 + kof, Bs + ldso);
      }
    }

#pragma unroll
    for (int ks = 0; ks < 2; ks++)
#pragma unroll
      for (int m = 0; m < 4; m++)
#pragma unroll
        for (int n = 0; n < 4; n++)
          acc[m][n] = __builtin_amdgcn_mfma_f32_16x16x32_bf16(
              af[ks][m], bf[ks][n], acc[m][n], 0, 0, 0);
  }

  // epilogue
#pragma unroll
  for (int m = 0; m < 4; m++) {
#pragma unroll
    for (int n = 0; n < 4; n++) {
      if (mode == 0) {
        int col = nb * 128 + wc * 64 + n * 16 + (lane & 15);  // n: [Q|K] 0..2047
        int wq = col >> 10;                                   // 0=Q 1=K
        float bs = wq ? bk[col & 1023] : bq[col & 1023];
        float scale = wq ? 1.0f : (0.125f * LOG2E);           // fold log2e into Q
        ushort* dst = wq ? Kg : Qg;
        int h = (col >> 6) & 15, d = col & 63;
#pragma unroll
        for (int r = 0; r < 4; r++) {
          int row = mb * 128 + wr * 64 + m * 16 + (lane >> 4) * 4 + r;  // b*2048+s
          int b = row >> 11, s = row & 2047;
          float v = (acc[m][n][r] + bs) * scale;
          dst[((size_t)((b << 4) + h) * 2048 + s) * 64 + d] = f2bf(v);
        }
      } else {
        int col = nb * 128 + wc * 64 + n * 16 + (lane & 15);  // m-index: b*2048+s
        int b = col >> 11, s = col & 2047;
#pragma unroll
        for (int r = 0; r < 4; r++) {
          int p = mb * 128 + wr * 64 + m * 16 + (lane >> 4) * 4 + r;  // h*64+d
          float v = acc[m][n][r] + bv[p];
          int h = p >> 6, d = p & 63;
          VTg[((size_t)((b << 4) + h) * 64 + d) * 2048 + s] = f2bf(v);
        }
      }
    }
  }
}

// ---------------------------------------------------------------------------
// Flash attention (R25): producer-consumer wave specialization.
// 512-thread blocks; waves 0-3 produce P (QK+softmax), waves 4-7 consume
// (PV).  P handoff: producer lane L's pf (PV B-operand) byte-copied to
// consumer lane L via Pb (lane-identity, conflict-free).  PV lags one kb
// phase; P dbuf by kb parity, V dbuf by kt parity.  Parity chain:
//   kt,kb: QK writes P(kt,kb)->par(kb&1); PV reads P(prev)->par(kb&1)^1,
//   V from Vs[kt&1] (kb>0) or Vs[(kt-1)&1] (kb==0); drain reads P(15,3).
__device__ __forceinline__ void pv_consume(
    const ushort* Pbase, const ushort* Vsb, int prev, int l31, int hi,
    f32x16* cacc) {
  __builtin_amdgcn_s_setprio(1);
#pragma unroll
  for (int w2 = 0; w2 < 2; w2++) {
    bf16x8 pf = *(const bf16x8*)(Pbase + w2 * 512);
    int w = prev * 2 + w2;
#pragma unroll
    for (int df = 0; df < 2; df++) {
      int d = df * 32 + l31;
      int c = (w * 2 + hi) ^ (d & 15);
      bf16x8 vf = *(const bf16x8*)(Vsb + d * 128 + c * 8);
      cacc[df] = __builtin_amdgcn_mfma_f32_32x32x16_bf16(vf, pf, cacc[df], 0, 0, 0);
    }
  }
  __builtin_amdgcn_s_setprio(0);
}

__global__ __launch_bounds__(512, 2) void attn_kernel(
    const ushort* __restrict__ Qg, const ushort* __restrict__ Kg,
    const ushort* __restrict__ VTg, const int* __restrict__ mask,
    const int* __restrict__ flagw, float* __restrict__ out) {
  __shared__ __align__(16) ushort Ks[128 * 64];      // 16KB pair-interleaved
  __shared__ __align__(16) ushort Vs[2][64 * 128];   // 2x16KB, kt-parity dbuf
  __shared__ __align__(16) ushort Pb[2][4][2][512];  // 16KB [par][pair][w2][lane*8]
  __shared__ float maddv[128];
  __shared__ float lsum[128];

  const int t = threadIdx.x, wid = t >> 6, lane = t & 63;
  const int l31 = lane & 31, hi = lane >> 5;
  const int qk = (wid < 4);                   // wave role
  const int pr_ = wid & 3;                    // pair index 0..3
  const int lin = blockIdx.x;
  const int lin2 = (lin & 7) * 128 + (lin >> 3);   // bijective XCD chunking
  const int qb = lin2 & 15, bh = lin2 >> 4;
  const int b = bh >> 4, h = bh & 15;
  const ushort* Qbh = Qg + ((size_t)bh * 2048 + qb * 128) * 64;
  const ushort* Kbh = Kg + (size_t)bh * 2048 * 64;
  const ushort* Vbh = VTg + (size_t)bh * 64 * 2048;

  // ---- staging lane constants: blki = i*8+wid => pr&15 = 4*(wid&3)+pr_l ----
  const int pr_l = lane >> 4;                 // 0..3 within issue
  const int s_l = lane & 15;
  const int spk = s_l ^ (4 * pr_ + pr_l);
  const int okl = 128 * pr_l + (spk >> 3) * 64 + (spk & 7) * 8;
  const int ovl = 2048 * pr_l + spk * 8;

  // ---- fragment-read lane constants ----
  const int prq = l31 >> 1;                   // phys row in 16-row group (0..15)
  const int hq8 = (l31 & 1) << 3;             // halfq<<3

  // ---- prologue: Q -> Ks (16 issues over 8 waves) ----
#pragma unroll
  for (int i = 0; i < 2; i++) {
    int blki = i * 8 + wid;
    int ldso = __builtin_amdgcn_readfirstlane(blki * 512);
    gload16(Qbh + blki * 512 + okl, Ks + ldso);
  }
  const int fb = flagw[b];
  __syncthreads();                            // Q staged
  bf16x8 qf[4];
  if (qk) {
    const ushort* qbase = Ks + (wid * 16 + prq) * 128;
#pragma unroll
    for (int ds = 0; ds < 4; ds++) {
      int slot = ((ds * 2 + hi) | hq8) ^ prq;
      qf[ds] = *(const bf16x8*)(qbase + slot * 8);
    }
  }
  __syncthreads();                            // qf read before Ks restage

  f32x16 cacc[2] = {};                        // PV waves only (live there)
  float l0 = 0.f, l1 = 0.f;                   // QK waves only

  for (int kt = 0; kt < 16; ++kt) {
    // ---- stage K(kt)->Ks, V(kt)->Vs[kt&1] (16+16 issues over 8 waves) ----
    {
      ushort* Vst = &Vs[kt & 1][0];
#pragma unroll
      for (int i = 0; i < 2; i++) {
        int blki = i * 8 + wid;
        int ldso = __builtin_amdgcn_readfirstlane(blki * 512);
        gload16(Kbh + kt * 8192 + blki * 512 + okl, Ks + ldso);
        gload16(Vbh + blki * 8192 + kt * 128 + ovl, Vst + ldso);
      }
    }
    const bool msk = ((fb >> kt) & 1) != 0;
    if (msk && t < 128)
      maddv[t] = (1.0f - (float)mask[b * 2048 + kt * 128 + t]) * (-10000.0f * LOG2E);
    __syncthreads();                          // tile kt staged (vmcnt drain)

#pragma unroll
    for (int kb = 0; kb < 4; kb++) {
      if (qk) {
        // ---- PRODUCE: QK (4 MFMA) -> exp2 -> pack -> P write ----
        const ushort* krow = Ks + (kb * 16 + prq) * 128;
        const f32x16 zz = {};
        __builtin_amdgcn_s_setprio(1);
        bf16x8 kf0 = *(const bf16x8*)(krow + (((0 + hi) | hq8) ^ prq) * 8);
        f32x16 a = __builtin_amdgcn_mfma_f32_32x32x16_bf16(kf0, qf[0], zz, 0, 0, 0);
        bf16x8 kf1 = *(const bf16x8*)(krow + (((2 + hi) | hq8) ^ prq) * 8);
        a = __builtin_amdgcn_mfma_f32_32x32x16_bf16(kf1, qf[1], a, 0, 0, 0);
        bf16x8 kf2 = *(const bf16x8*)(krow + (((4 + hi) | hq8) ^ prq) * 8);
        a = __builtin_amdgcn_mfma_f32_32x32x16_bf16(kf2, qf[2], a, 0, 0, 0);
        bf16x8 kf3 = *(const bf16x8*)(krow + (((6 + hi) | hq8) ^ prq) * 8);
        a = __builtin_amdgcn_mfma_f32_32x32x16_bf16(kf3, qf[3], a, 0, 0, 0);
        __builtin_amdgcn_s_setprio(0);

        if (msk) {
#pragma unroll
          for (int qd = 0; qd < 4; qd++) {
            f32x4 ma = *(const f32x4*)(maddv + kb * 32 + qd * 8 + hi * 4);
#pragma unroll
            for (int rr = 0; rr < 4; rr++) a[qd * 4 + rr] += ma[rr];
          }
        }

#pragma unroll
        for (int w2 = 0; w2 < 2; w2++) {
          const int o = w2 * 8;
          float e0 = __builtin_amdgcn_exp2f(a[o + 0]);
          float e1 = __builtin_amdgcn_exp2f(a[o + 1]);
          float e2 = __builtin_amdgcn_exp2f(a[o + 2]);
          float e3 = __builtin_amdgcn_exp2f(a[o + 3]);
          float e4 = __builtin_amdgcn_exp2f(a[o + 4]);
          float e5 = __builtin_amdgcn_exp2f(a[o + 5]);
          float e6 = __builtin_amdgcn_exp2f(a[o + 6]);
          float e7 = __builtin_amdgcn_exp2f(a[o + 7]);
          l0 += e0; l1 += e1; l0 += e2; l1 += e3;
          l0 += e4; l1 += e5; l0 += e6; l1 += e7;
          unsigned a0, a1, b0, b1;
          asm("v_cvt_pk_bf16_f32 %0, %1, %2" : "=v"(a0) : "v"(e0), "v"(e1));
          asm("v_cvt_pk_bf16_f32 %0, %1, %2" : "=v"(a1) : "v"(e2), "v"(e3));
          asm("v_cvt_pk_bf16_f32 %0, %1, %2" : "=v"(b0) : "v"(e4), "v"(e5));
          asm("v_cvt_pk_bf16_f32 %0, %1, %2" : "=v"(b1) : "v"(e6), "v"(e7));
          asm("v_permlane32_swap_b32 %0, %1" : "+v"(a0), "+v"(b0));
          asm("v_permlane32_swap_b32 %0, %1" : "+v"(a1), "+v"(b1));
          union { unsigned u[4]; bf16x8 v8; } pu;
          pu.u[0] = a0; pu.u[1] = a1; pu.u[2] = b0; pu.u[3] = b1;
          *(bf16x8*)&Pb[kb & 1][wid][w2][lane * 8] = pu.v8;
        }
      } else if (kt + kb > 0) {
        // ---- CONSUME: P(prev) x V -> cacc (prev = kb-1 mod 4) ----
        const int prev = (kb + 3) & 3;
        const ushort* Vsb = &Vs[(kb == 0) ? ((kt + 1) & 1) : (kt & 1)][0];
        const ushort* Pbase = &Pb[prev & 1][wid - 4][0][lane * 8];
        pv_consume(Pbase, Vsb, prev, l31, hi, cacc);
      }
      __syncthreads();                        // P(kb) ready / P(prev) freed
    }
  }

  // ---- drain + epilogue ----
  if (qk) {
    float lrun = l0 + l1;
    lrun += __shfl_xor(lrun, 32);
    if (lane < 32) lsum[wid * 32 + lane] = 1.0f / lrun;
  } else {
    // consume P(15,3): parity 1, V(15) = Vs[1]
    const ushort* Pbase = &Pb[1][wid - 4][0][lane * 8];
    pv_consume(Pbase, &Vs[1][0], 3, l31, hi, cacc);
  }
  __syncthreads();
  if (!qk) {
    float linv = lsum[(wid - 4) * 32 + l31];
    int qg = qb * 128 + (wid - 4) * 32 + l31;
    float* op = out + ((size_t)(b * 2048 + qg)) * 1024 + h * 64;
#pragma unroll
    for (int df = 0; df < 2; df++)
#pragma unroll
      for (int qd = 0; qd < 4; qd++) {
        f32x4 v;
        v[0] = cacc[df][qd * 4 + 0] * linv;
        v[1] = cacc[df][qd * 4 + 1] * linv;
        v[2] = cacc[df][qd * 4 + 2] * linv;
        v[3] = cacc[df][qd * 4 + 3] * linv;
        *(f32x4*)(op + df * 32 + qd * 8 + hi * 4) = v;
      }
  }
}

// ---------------------------------------------------------------------------
extern "C" void kernel_launch(void* const* d_in, const int* in_sizes, int n_in,
                              void* d_out, int out_size, void* d_ws, size_t ws_size,
                              hipStream_t stream) {
  const float* x  = (const float*)d_in[0];
  const int* mask = (const int*)d_in[1];
  const float* Wq = (const float*)d_in[2];
  const float* bq = (const float*)d_in[3];
  const float* Wk = (const float*)d_in[4];
  const float* bk = (const float*)d_in[5];
  const float* Wv = (const float*)d_in[6];
  const float* bv = (const float*)d_in[7];
  float* out = (float*)d_out;

  char* ws = (char*)d_ws;
  ushort* xb  = (ushort*)(ws);                                  // 16 MB
  ushort* WT  = (ushort*)(ws + (size_t)16777216);               // 6 MB
  ushort* Qg  = (ushort*)(ws + (size_t)23068672);               // 16 MB
  ushort* Kg  = (ushort*)(ws + (size_t)39845888);               // 16 MB
  ushort* VTg = (ushort*)(ws + (size_t)56623104);               // 16 MB
  int*    flg = (int*)(ws + (size_t)73400320);                  // 16 B

  prep<<<dim3(11265), dim3(256), 0, stream>>>(x, xb, Wq, Wk, Wv, WT, mask, flg);
  gemm_qkv<<<dim3(1536), dim3(256), 0, stream>>>(xb, WT, bq, bk, bv, Qg, Kg, VTg);
  attn_kernel<<<dim3(1024), dim3(512), 0, stream>>>(Qg, Kg, VTg, mask, flg, out);
}